// Round 15
// baseline (317.743 us; speedup 1.0000x reference)
//
#include <hip/hip_runtime.h>
#include <math.h>

#define EPS 1e-5f

typedef __attribute__((ext_vector_type(8))) short s16x8;   // 8 bf16 (4 VGPRs)
typedef __attribute__((ext_vector_type(4))) float f32x4;   // MFMA C/D

__device__ __forceinline__ unsigned short f2bf(float x) {
    unsigned u = __float_as_uint(x);
    u += 0x7fffu + ((u >> 16) & 1u);           // round-to-nearest-even
    return (unsigned short)(u >> 16);
}
__device__ __forceinline__ float bf2f(unsigned short h) {
    return __uint_as_float(((unsigned)h) << 16);
}
__device__ __forceinline__ unsigned long long pack4bf(float a, float b, float c, float d) {
    return (unsigned long long)f2bf(a)
         | ((unsigned long long)f2bf(b) << 16)
         | ((unsigned long long)f2bf(c) << 32)
         | ((unsigned long long)f2bf(d) << 48);
}

// ---- DPP width-16 reductions (pure VALU, no LDS pipe)
template<int CTRL>
__device__ __forceinline__ float dppmov(float x) {
    return __int_as_float(__builtin_amdgcn_update_dpp(
        0, __float_as_int(x), CTRL, 0xF, 0xF, true));
}
__device__ __forceinline__ float red16_sum(float x) {
    x += dppmov<0xB1>(x);
    x += dppmov<0x4E>(x);
    x += dppmov<0x141>(x);
    x += dppmov<0x140>(x);
    return x;
}
__device__ __forceinline__ float red16_max(float x) {
    x = fmaxf(x, dppmov<0xB1>(x));
    x = fmaxf(x, dppmov<0x4E>(x));
    x = fmaxf(x, dppmov<0x141>(x));
    x = fmaxf(x, dppmov<0x140>(x));
    return x;
}

// ---------------------------------------------------------------- K1: knn + point moments + weight bf16 conversion + bin/bar zeroing.
__global__ __launch_bounds__(128) void k1_prep(
    const float* __restrict__ pg,
    const float* __restrict__ W2, const float* __restrict__ W3,
    const float* __restrict__ W4, const float* __restrict__ Wf,
    float* __restrict__ mom, int* __restrict__ idxw,
    unsigned short* __restrict__ W2b, unsigned short* __restrict__ W3b,
    unsigned short* __restrict__ W4b, unsigned short* __restrict__ Wfb,
    float* __restrict__ p3sb, float* __restrict__ p3qb,
    unsigned* __restrict__ barcnt)
{
    __shared__ float pgs[96];
    __shared__ float sqs[32];
    if (blockIdx.x >= 1024) {
        const int wb = blockIdx.x - 1024;
        const int i = wb * 128 + threadIdx.x;
        if (i < 32768)  W2b[i] = f2bf(W2[i]);
        if (i < 262144) W3b[i] = f2bf(W3[i]);
        if (i < 196608) W4b[i] = f2bf(W4[i]);
        if (i < 294912) Wfb[i] = f2bf(Wf[i]);
        if (wb < 16) {
            for (int j = threadIdx.x; j < 512; j += 128) {
                p3sb[wb*512 + j] = 0.f;
                p3qb[wb*512 + j] = 0.f;
            }
        }
        if (wb == 16 && threadIdx.x < 2) barcnt[threadIdx.x] = 0u;
        return;
    }
    const int b = blockIdx.x;
    const int t = threadIdx.x;
    if (t < 96) pgs[t] = pg[b * 96 + t];
    __syncthreads();
    if (t < 32) {
        float x = pgs[t*3+0], y = pgs[t*3+1], z = pgs[t*3+2];
        sqs[t] = x*x + y*y + z*z;
    }
    __syncthreads();
    if (t < 32) {
        const float x = pgs[t*3+0], y = pgs[t*3+1], z = pgs[t*3+2];
        float v[9] = {x, y, z, x*x, x*y, x*z, y*y, y*z, z*z};
        #pragma unroll
        for (int off = 16; off > 0; off >>= 1)
            #pragma unroll
            for (int j = 0; j < 9; ++j)
                v[j] += __shfl_down(v[j], off, 32);
        if (t == 0) {
            #pragma unroll
            for (int j = 0; j < 9; ++j)
                mom[j*1024 + b] = v[j];
        }
        const float sql = sqs[t];
        float dist[32];
        #pragma unroll
        for (int m = 0; m < 32; ++m) {
            float dot = x*pgs[m*3+0] + y*pgs[m*3+1] + z*pgs[m*3+2];
            dist[m] = sql + sqs[m] - 2.f*dot;
        }
        unsigned used = 0u;
        int* orow = idxw + b*256 + t*8;
        #pragma unroll
        for (int j = 0; j < 8; ++j) {
            float best = 3.4e38f; int bi = 0;
            #pragma unroll
            for (int m = 0; m < 32; ++m) {
                if (!((used >> m) & 1u) && dist[m] < best) { best = dist[m]; bi = m; }
            }
            used |= (1u << bi);
            orow[j] = bi;
        }
    }
}

// ---------------------------------------------------------------- K35: fused k3+BN3+k5, grid 512 x 1024 thr.
// Fence-free grid barrier: cross-block data = ONLY the atomic p3 bins (device-
// coherent by construction; drained by the vmcnt(0) in __syncthreads before
// arrival). Each block re-reads only its OWN h3b slice (own-XCD L2 hot).
// Co-residency: 74.9KB LDS x2 <= 160KB, 32 waves/CU, <=64 VGPR -> all 512
// blocks resident, spin cannot deadlock.
__global__ __launch_bounds__(1024, 8) void k35_fused(
    const float* __restrict__ pg,
    const float* __restrict__ W1, const float* __restrict__ b1,
    const float* __restrict__ gamma1, const float* __restrict__ beta1,
    const float* __restrict__ mom,
    const unsigned short* __restrict__ W2b, const float* __restrict__ b2,
    const unsigned short* __restrict__ W3b, const float* __restrict__ b3,
    const float* __restrict__ gamma3, const float* __restrict__ beta3,
    const unsigned short* __restrict__ W4b, const float* __restrict__ b4,
    const int* __restrict__ idxw,
    unsigned short* __restrict__ h3b,
    float* __restrict__ p3sb, float* __restrict__ p3qb,
    unsigned* __restrict__ barcnt,
    float* __restrict__ fg2, float* __restrict__ A,
    float* __restrict__ S1p, float* __restrict__ S2p)
{
    const int g0 = blockIdx.x * 2;
    const int t = threadIdx.x;
    __shared__ __align__(16) unsigned short SB[33280];   // 66560 B (phaseA uses 52256; phaseB B4/XT/Mm alias)
    unsigned short* B1  = SB;            // [64][136] conv2 staging
    unsigned short* F2  = SB + 8704;     // [64][264] f2, conv3 B-matrix
    unsigned short* FGB = SB + 25600;    // [2][264] fg per group
    unsigned short* B4  = SB;            // [64][520] conv4 B-matrix (phase B)
    unsigned short* XT  = SB;            // [g][o*40 + l], g stride 15360
    unsigned short* Mm  = SB + 30720;    // [g][l*40 + m], g stride 1280
    __shared__ __align__(16) float sc1s[128], sh1s[128];
    __shared__ __align__(16) float W1s[384], b1s[128];
    __shared__ __align__(16) float pgs3[192];
    __shared__ float momS[9];
    __shared__ __align__(16) float sc3s[512], sh3s[512];
    __shared__ int icnt[2][32];
    __shared__ float r1[2][12], r2[2][12];

    // ================= Phase A (old k3) =================
    if (t < 192) pgs3[t] = pg[g0*96 + t];
    if (t < 384) W1s[t] = W1[t];
    if (t < 128) b1s[t] = b1[t];
    {
        const int wv = t >> 6, ln = t & 63;
        if (wv < 9) {
            float s = 0.f;
            #pragma unroll
            for (int i = 0; i < 16; ++i)
                s += mom[wv*1024 + ln + 64*i];
            #pragma unroll
            for (int off = 32; off > 0; off >>= 1)
                s += __shfl_down(s, off, 64);
            if (ln == 0) momS[wv] = s;
        }
    }
    __syncthreads();

    if (t < 128) {
        const float Sx = momS[0], Sy = momS[1], Sz = momS[2];
        const float Sxx = momS[3], Sxy = momS[4], Sxz = momS[5];
        const float Syy = momS[6], Syz = momS[7], Szz = momS[8];
        const float w0 = W1s[t*3+0], w1 = W1s[t*3+1], w2 = W1s[t*3+2];
        const float bb = b1s[t];
        const float N = 32768.f;
        const float wd = w0*Sx + w1*Sy + w2*Sz;
        const float S = wd + N*bb;
        const float Q = w0*w0*Sxx + w1*w1*Syy + w2*w2*Szz
                      + 2.f*(w0*w1*Sxy + w0*w2*Sxz + w1*w2*Syz)
                      + 2.f*bb*wd + N*bb*bb;
        const float mu  = S * (1.f/32768.f);
        const float var = Q * (1.f/32768.f) - mu*mu;
        const float sc  = gamma1[t] * rsqrtf(var + EPS);
        sc1s[t] = sc;
        sh1s[t] = beta1[t] - mu * sc;
    }
    __syncthreads();

    {
        const int l = t >> 4, c0 = (t & 15) * 8;
        const float px = pgs3[l*3+0], py = pgs3[l*3+1], pz = pgs3[l*3+2];
        unsigned short ov[8];
        #pragma unroll
        for (int e = 0; e < 8; ++e) {
            const int c = c0 + e;
            float v = fmaf(W1s[c*3+2], pz, fmaf(W1s[c*3+1], py, fmaf(W1s[c*3+0], px, b1s[c])));
            float val = fmaxf(fmaf(v, sc1s[c], sh1s[c]), 0.f);
            ov[e] = f2bf(val);
        }
        uint4 o4;
        o4.x = (unsigned)ov[0] | ((unsigned)ov[1] << 16);
        o4.y = (unsigned)ov[2] | ((unsigned)ov[3] << 16);
        o4.z = (unsigned)ov[4] | ((unsigned)ov[5] << 16);
        o4.w = (unsigned)ov[6] | ((unsigned)ov[7] << 16);
        *(uint4*)&B1[l*136 + c0] = o4;
    }
    __syncthreads();

    const int wave = t >> 6;      // 0..15
    const int lane = t & 63;
    const int m    = lane & 15;
    const int quad = lane >> 4;

    f32x4 acc2[4];
    #pragma unroll
    for (int n = 0; n < 4; ++n)
        acc2[n] = (f32x4){0.f, 0.f, 0.f, 0.f};

    #pragma unroll
    for (int kt = 0; kt < 4; ++kt) {
        s16x8 bv[4];
        #pragma unroll
        for (int nt = 0; nt < 4; ++nt)
            bv[nt] = *(const s16x8*)&B1[(nt*16 + m)*136 + kt*32 + quad*8];
        s16x8 av = *(const s16x8*)(W2b + (size_t)(wave*16 + m)*128 + kt*32 + quad*8);
        #pragma unroll
        for (int nt = 0; nt < 4; ++nt)
            acc2[nt] = __builtin_amdgcn_mfma_f32_16x16x32_bf16(av, bv[nt], acc2[nt], 0, 0, 0);
    }

    {
        const int o0 = wave*16 + quad*4;
        #pragma unroll
        for (int r = 0; r < 4; ++r) {
            float bb = b2[o0 + r];
            #pragma unroll
            for (int nt = 0; nt < 4; ++nt) acc2[nt][r] += bb;
        }
        #pragma unroll
        for (int nt = 0; nt < 4; ++nt) {
            const int row = nt*16 + m;
            *(unsigned long long*)&F2[row*264 + o0] =
                pack4bf(acc2[nt][0], acc2[nt][1], acc2[nt][2], acc2[nt][3]);
        }
        float f0[4], f1[4];
        #pragma unroll
        for (int r = 0; r < 4; ++r) {
            f0[r] = red16_max(fmaxf(acc2[0][r], acc2[1][r]));
            f1[r] = red16_max(fmaxf(acc2[2][r], acc2[3][r]));
        }
        if (m == 0) {
            *(unsigned long long*)&FGB[o0]       = pack4bf(f0[0], f0[1], f0[2], f0[3]);
            *(unsigned long long*)&FGB[264 + o0] = pack4bf(f1[0], f1[1], f1[2], f1[3]);
        }
    }
    __syncthreads();   // F2 + FGB complete

    unsigned short* dst = h3b + (size_t)blockIdx.x * 32768;
    const int binbase = (blockIdx.x & 15) * 512;
    #pragma unroll
    for (int mt = 0; mt < 2; ++mt) {
        const int ot = wave*2 + mt;          // 0..31
        const int o0 = ot*16 + quad*4;

        f32x4 facc = (f32x4){0.f, 0.f, 0.f, 0.f};
        #pragma unroll
        for (int kt = 0; kt < 8; ++kt) {
            s16x8 bg = *(const s16x8*)&FGB[(m & 1)*264 + kt*32 + quad*8];
            s16x8 av = *(const s16x8*)(W3b + (size_t)(ot*16 + m)*512 + kt*32 + quad*8);
            facc = __builtin_amdgcn_mfma_f32_16x16x32_bf16(av, bg, facc, 0, 0, 0);
        }

        f32x4 acc3[4];
        #pragma unroll
        for (int r = 0; r < 4; ++r) {
            float self = facc[r];
            float oth  = dppmov<0xB1>(self);        // value from lane m^1
            float fg_g0 = (m & 1) ? oth : self;
            float fg_g1 = (m & 1) ? self : oth;
            float bb = b3[o0 + r];
            acc3[0][r] = bb + fg_g0;
            acc3[1][r] = bb + fg_g0;
            acc3[2][r] = bb + fg_g1;
            acc3[3][r] = bb + fg_g1;
        }

        #pragma unroll
        for (int kt = 0; kt < 8; ++kt) {
            s16x8 bv[4];
            #pragma unroll
            for (int nt = 0; nt < 4; ++nt)
                bv[nt] = *(const s16x8*)&F2[(nt*16 + m)*264 + kt*32 + quad*8];
            s16x8 av = *(const s16x8*)(W3b + (size_t)(ot*16 + m)*512 + 256 + kt*32 + quad*8);
            #pragma unroll
            for (int nt = 0; nt < 4; ++nt)
                acc3[nt] = __builtin_amdgcn_mfma_f32_16x16x32_bf16(av, bv[nt], acc3[nt], 0, 0, 0);
        }

        float s[4], q[4];
        #pragma unroll
        for (int r = 0; r < 4; ++r) {
            float x0 = acc3[0][r], x1 = acc3[1][r];
            float x2 = acc3[2][r], x3 = acc3[3][r];
            s[r] = (x0 + x1) + (x2 + x3);
            q[r] = (x0*x0 + x1*x1) + (x2*x2 + x3*x3);
        }
        {
            unsigned long long u0 = pack4bf(acc3[0][0], acc3[0][1], acc3[0][2], acc3[0][3]);
            unsigned long long u1 = pack4bf(acc3[1][0], acc3[1][1], acc3[1][2], acc3[1][3]);
            unsigned long long u2 = pack4bf(acc3[2][0], acc3[2][1], acc3[2][2], acc3[2][3]);
            unsigned long long u3 = pack4bf(acc3[3][0], acc3[3][1], acc3[3][2], acc3[3][3]);
            unsigned short* p = dst + (size_t)(ot*64 + lane) * 16;
            *(uint4*)(p)     = make_uint4((unsigned)u0, (unsigned)(u0 >> 32), (unsigned)u1, (unsigned)(u1 >> 32));
            *(uint4*)(p + 8) = make_uint4((unsigned)u2, (unsigned)(u2 >> 32), (unsigned)u3, (unsigned)(u3 >> 32));
        }
        #pragma unroll
        for (int r = 0; r < 4; ++r) {
            s[r] = red16_sum(s[r]);
            q[r] = red16_sum(q[r]);
        }
        if (m == 0) {
            #pragma unroll
            for (int r = 0; r < 4; ++r) {
                atomicAdd(&p3sb[binbase + o0 + r], s[r]);
                atomicAdd(&p3qb[binbase + o0 + r], q[r]);
            }
        }
    }

    // ================= fence-free grid barrier =================
    // __syncthreads drains this block's atomics/stores (vmcnt 0 before barrier);
    // cross-block data is ONLY the device-scope atomic bins.
    __syncthreads();
    if (t == 0) {
        __hip_atomic_fetch_add(&barcnt[0], 1u, __ATOMIC_ACQ_REL, __HIP_MEMORY_SCOPE_AGENT);
        while (__hip_atomic_load(&barcnt[0], __ATOMIC_ACQUIRE, __HIP_MEMORY_SCOPE_AGENT) < 512u)
            __builtin_amdgcn_s_sleep(8);
    }
    __syncthreads();

    // ---- BN3 finalize from 16 bins (device-scope loads bypass stale L2)
    if (t < 512) {
        float S = 0.f, Q = 0.f;
        #pragma unroll
        for (int bb = 0; bb < 16; ++bb) {
            S += __hip_atomic_load(&p3sb[bb*512 + t], __ATOMIC_RELAXED, __HIP_MEMORY_SCOPE_AGENT);
            Q += __hip_atomic_load(&p3qb[bb*512 + t], __ATOMIC_RELAXED, __HIP_MEMORY_SCOPE_AGENT);
        }
        float mu  = S * (1.f/32768.f);
        float var = Q * (1.f/32768.f) - mu*mu;
        float sc  = gamma3[t] * rsqrtf(var + EPS);
        sc3s[t] = sc;
        sh3s[t] = beta3[t] - mu * sc;
    }
    if (t < 64) icnt[t >> 5][t & 31] = 0;
    __syncthreads();

    // ================= Phase B (old k5; own h3b slice is L2-hot) =================
    {
        const uint4* src = (const uint4*)(h3b + (size_t)blockIdx.x * 32768);
        for (int i = t; i < 4096; i += 1024) {
            uint4 hv = src[i];
            const int flat16 = i >> 1, half = i & 1;
            const int ln = flat16 & 63, m2 = ln & 15, q2 = ln >> 4;
            const int wm = flat16 >> 6;
            const int o0 = wm*16 + q2*4;
            const float4 sc = *(const float4*)&sc3s[o0];
            const float4 sh = *(const float4*)&sh3s[o0];
            const int rowa = (half*2)*16 + m2;
            float a0 = fmaxf(fmaf(bf2f((unsigned short)(hv.x       )), sc.x, sh.x), 0.f);
            float a1 = fmaxf(fmaf(bf2f((unsigned short)(hv.x >> 16 )), sc.y, sh.y), 0.f);
            float a2 = fmaxf(fmaf(bf2f((unsigned short)(hv.y       )), sc.z, sh.z), 0.f);
            float a3 = fmaxf(fmaf(bf2f((unsigned short)(hv.y >> 16 )), sc.w, sh.w), 0.f);
            float b0 = fmaxf(fmaf(bf2f((unsigned short)(hv.z       )), sc.x, sh.x), 0.f);
            float b1 = fmaxf(fmaf(bf2f((unsigned short)(hv.z >> 16 )), sc.y, sh.y), 0.f);
            float b2 = fmaxf(fmaf(bf2f((unsigned short)(hv.w       )), sc.z, sh.z), 0.f);
            float b3 = fmaxf(fmaf(bf2f((unsigned short)(hv.w >> 16 )), sc.w, sh.w), 0.f);
            *(unsigned long long*)&B4[rowa*520 + o0]        = pack4bf(a0, a1, a2, a3);
            *(unsigned long long*)&B4[(rowa + 16)*520 + o0] = pack4bf(b0, b1, b2, b3);
        }
    }
    __syncthreads();

    f32x4 acc4[2][4];
    #pragma unroll
    for (int mt = 0; mt < 2; ++mt)
        #pragma unroll
        for (int n = 0; n < 4; ++n)
            acc4[mt][n] = (f32x4){0.f, 0.f, 0.f, 0.f};

    if (wave < 12) {
        #pragma unroll 4
        for (int kt = 0; kt < 16; ++kt) {
            s16x8 bv[4];
            #pragma unroll
            for (int nt = 0; nt < 4; ++nt)
                bv[nt] = *(const s16x8*)&B4[(nt*16 + m)*520 + kt*32 + quad*8];
            #pragma unroll
            for (int mt = 0; mt < 2; ++mt) {
                s16x8 av = *(const s16x8*)(W4b + (size_t)(wave*32 + mt*16 + m)*512 + kt*32 + quad*8);
                #pragma unroll
                for (int nt = 0; nt < 4; ++nt)
                    acc4[mt][nt] = __builtin_amdgcn_mfma_f32_16x16x32_bf16(av, bv[nt], acc4[mt][nt], 0, 0, 0);
            }
        }

        #pragma unroll
        for (int mt = 0; mt < 2; ++mt) {
            const int o0 = wave*32 + mt*16 + quad*4;
            float f0[4], f1[4];
            #pragma unroll
            for (int r = 0; r < 4; ++r) {
                float bb = b4[o0 + r];
                #pragma unroll
                for (int nt = 0; nt < 4; ++nt) acc4[mt][nt][r] += bb;
                f0[r] = red16_max(fmaxf(acc4[mt][0][r], acc4[mt][1][r]));
                f1[r] = red16_max(fmaxf(acc4[mt][2][r], acc4[mt][3][r]));
            }
            if (m == 0) {
                #pragma unroll
                for (int r = 0; r < 4; ++r) {
                    fg2[(size_t)g0*384 + o0 + r]     = f0[r];
                    fg2[(size_t)(g0+1)*384 + o0 + r] = f1[r];
                }
            }
        }
    }
    __syncthreads();   // B4 reads done; SB becomes XT/Mm

    if (wave < 12) {
        #pragma unroll
        for (int mt = 0; mt < 2; ++mt) {
            const int o0 = wave*32 + mt*16 + quad*4;
            #pragma unroll
            for (int nt = 0; nt < 4; ++nt) {
                const int g = nt >> 1;
                const int l = (nt & 1)*16 + m;
                unsigned short* xg = XT + g*15360;
                #pragma unroll
                for (int r = 0; r < 4; ++r)
                    xg[(o0 + r)*40 + l] = f2bf(acc4[mt][nt][r]);
            }
        }
    }
    if (t < 64) {
        const int g = t >> 5, l = t & 31;
        uint4 z = make_uint4(0u, 0u, 0u, 0u);
        #pragma unroll
        for (int i = 0; i < 5; ++i)
            *(uint4*)&Mm[g*1280 + l*40 + i*8] = z;
    }
    __syncthreads();

    if (t < 64) {
        const int g = t >> 5, l = t & 31;
        const int* ip = idxw + (size_t)(g0 + g)*256 + l*8;
        #pragma unroll
        for (int j = 0; j < 8; ++j) {
            int ix = ip[j];
            Mm[g*1280 + l*40 + ix] = 0x3F80;
            atomicAdd(&icnt[g][ix], 1);
        }
    }
    __syncthreads();

    float s1loc[2] = {0.f, 0.f}, s2loc[2] = {0.f, 0.f};
    if (wave < 12) {
        #pragma unroll
        for (int g = 0; g < 2; ++g) {
            const float c0 = (float)icnt[g][m];
            const float c1 = (float)icnt[g][m + 16];
            const float w0 = c0 - 8.f, u0 = c0 + 8.f;
            const float w1 = c1 - 8.f, u1 = c1 + 8.f;
            #pragma unroll
            for (int mt = 0; mt < 2; ++mt) {
                const int o0 = wave*32 + mt*16 + quad*4;
                float Ap[4];
                #pragma unroll
                for (int r = 0; r < 4; ++r) {
                    const float x0 = acc4[mt][g*2 + 0][r];
                    const float x1 = acc4[mt][g*2 + 1][r];
                    Ap[r] = w0*x0 + w1*x1;
                    s1loc[g] += Ap[r];
                    s2loc[g] += u0*x0*x0 + u1*x1*x1;
                }
                #pragma unroll
                for (int r = 0; r < 4; ++r)
                    Ap[r] = red16_sum(Ap[r]);
                if (m == 0) {
                    #pragma unroll
                    for (int r = 0; r < 4; ++r)
                        A[(size_t)(g0 + g)*384 + o0 + r] = Ap[r];
                }
            }
        }

        #pragma unroll
        for (int g = 0; g < 2; ++g) {
            const unsigned short* xg = XT + g*15360;
            float cross = 0.f;
            #pragma unroll
            for (int lt = 0; lt < 2; ++lt) {
                s16x8 af = *(const s16x8*)&Mm[g*1280 + (lt*16 + m)*40 + quad*8];
                #pragma unroll
                for (int i = 0; i < 2; ++i) {
                    const int oc = (wave*2 + i)*16 + m;
                    s16x8 bfv = *(const s16x8*)&xg[oc*40 + quad*8];
                    f32x4 sa = __builtin_amdgcn_mfma_f32_16x16x32_bf16(
                        af, bfv, (f32x4){0.f, 0.f, 0.f, 0.f}, 0, 0, 0);
                    #pragma unroll
                    for (int r = 0; r < 4; ++r) {
                        const int lp = lt*16 + quad*4 + r;
                        cross = fmaf(bf2f(xg[oc*40 + lp]), sa[r], cross);
                    }
                }
            }
            s2loc[g] -= 2.f * cross;
        }
    }

    #pragma unroll
    for (int g = 0; g < 2; ++g) {
        float sA = s1loc[g], sQ = s2loc[g];
        #pragma unroll
        for (int off = 32; off > 0; off >>= 1) {
            sA += __shfl_down(sA, off, 64);
            sQ += __shfl_down(sQ, off, 64);
        }
        if (lane == 0 && wave < 12) { r1[g][wave] = sA; r2[g][wave] = sQ; }
    }
    __syncthreads();
    if (t < 2) {
        float S = 0.f, Q = 0.f;
        #pragma unroll
        for (int w = 0; w < 12; ++w) { S += r1[t][w]; Q += r2[t][w]; }
        S1p[g0 + t] = S;
        S2p[g0 + t] = Q;
    }
}

// ---------------------------------------------------------------- K7: head GEMM, M split 4-ways -> grid 256.
__global__ __launch_bounds__(384) void k7_fused(
    const float* __restrict__ fg2, const float* __restrict__ A,
    const float* __restrict__ alpha, const float* __restrict__ beta_aff,
    const float* __restrict__ S1p, const float* __restrict__ S2p,
    const unsigned short* __restrict__ Wfb, const float* __restrict__ bf,
    float* __restrict__ hf, float* __restrict__ pfs, float* __restrict__ pfq)
{
    const int blk    = blockIdx.x;
    const int slice  = blk >> 2;          // 0..63 (group slice)
    const int msplit = blk & 3;           // 0..3  (channel quarter)
    const int g0     = slice * 16;
    const int obase  = msplit * 96;
    const int t = threadIdx.x;
    __shared__ __align__(16) char smem[24832];
    unsigned short* xfb = (unsigned short*)smem;   // [16][776] bf16 inputs
    float* OTf = (float*)smem;                     // [16][100] fp32 out (aliases xfb, sync'd)
    __shared__ double rs[6], rq[6];
    __shared__ float stdsh;

    {
        double s = 0.0, q = 0.0;
        for (int i = t; i < 1024; i += 384) { s += (double)S1p[i]; q += (double)S2p[i]; }
        #pragma unroll
        for (int off = 32; off > 0; off >>= 1) {
            s += __shfl_down(s, off, 64);
            q += __shfl_down(q, off, 64);
        }
        if ((t & 63) == 0) { rs[t >> 6] = s; rq[t >> 6] = q; }
        __syncthreads();
        if (t == 0) {
            double S = 0.0, Q = 0.0;
            #pragma unroll
            for (int w = 0; w < 6; ++w) { S += rs[w]; Q += rq[w]; }
            const double N = 1024.0 * 32.0 * 8.0 * 384.0;
            double var = (Q - S*S/N) / (N - 1.0);
            stdsh = (float)sqrt(var);
        }
        __syncthreads();
    }
    const float inv = 1.f / (256.f * (stdsh + EPS));

    for (int i = t; i < 16*96; i += 384) {
        const int row = i / 96, c8 = (i % 96) * 8;
        const int g = g0 + row;
        float e[8];
        if (c8 < 384) {
            const float4* s0 = (const float4*)(fg2 + (size_t)g*384 + c8);
            float4 v0 = s0[0], v1 = s0[1];
            e[0]=v0.x; e[1]=v0.y; e[2]=v0.z; e[3]=v0.w;
            e[4]=v1.x; e[5]=v1.y; e[6]=v1.z; e[7]=v1.w;
        } else {
            const int cc = c8 - 384;
            const float4* s0 = (const float4*)(A + (size_t)g*384 + cc);
            float4 v0 = s0[0], v1 = s0[1];
            float av[8] = {v0.x,v0.y,v0.z,v0.w,v1.x,v1.y,v1.z,v1.w};
            #pragma unroll
            for (int j = 0; j < 8; ++j)
                e[j] = fmaf(alpha[cc+j] * inv, av[j], beta_aff[cc+j]);
        }
        uint4 o4;
        o4.x = (unsigned)f2bf(e[0]) | ((unsigned)f2bf(e[1]) << 16);
        o4.y = (unsigned)f2bf(e[2]) | ((unsigned)f2bf(e[3]) << 16);
        o4.z = (unsigned)f2bf(e[4]) | ((unsigned)f2bf(e[5]) << 16);
        o4.w = (unsigned)f2bf(e[6]) | ((unsigned)f2bf(e[7]) << 16);
        *(uint4*)&xfb[row*776 + c8] = o4;
    }
    __syncthreads();

    const int wave = t >> 6;      // 0..5
    const int lane = t & 63;
    const int m    = lane & 15;
    const int quad = lane >> 4;

    f32x4 acc = (f32x4){0.f, 0.f, 0.f, 0.f};
    #pragma unroll 4
    for (int kt = 0; kt < 24; ++kt) {
        s16x8 bv = *(const s16x8*)&xfb[m*776 + kt*32 + quad*8];
        s16x8 av = *(const s16x8*)(Wfb + (size_t)(obase + wave*16 + m)*768 + kt*32 + quad*8);
        acc = __builtin_amdgcn_mfma_f32_16x16x32_bf16(av, bv, acc, 0, 0, 0);
    }

    {
        const int o0 = obase + wave*16 + quad*4;
        float s[4], q[4];
        #pragma unroll
        for (int r = 0; r < 4; ++r) {
            acc[r] += bf[o0 + r];
            s[r] = red16_sum(acc[r]);
            q[r] = red16_sum(acc[r]*acc[r]);
        }
        if (m == 0) {
            #pragma unroll
            for (int r = 0; r < 4; ++r) {
                pfs[(size_t)slice*384 + o0 + r] = s[r];
                pfq[(size_t)slice*384 + o0 + r] = q[r];
            }
        }
    }
    __syncthreads();   // xfb reads done; smem becomes OTf

    {
        const int lo0 = wave*16 + quad*4;     // local channel 0..95
        #pragma unroll
        for (int r = 0; r < 4; ++r)
            OTf[m*100 + lo0 + r] = acc[r];
    }
    __syncthreads();

    {
        const int grp = t / 24, c4 = t % 24;
        float4 v = *(const float4*)&OTf[grp*100 + c4*4];
        *(float4*)(hf + (size_t)(g0 + grp)*384 + obase + c4*4) = v;
    }
}

// ---------------------------------------------------------------- K9: fused BNf finalize (redundant per-block) + relu -> out
__global__ __launch_bounds__(384) void k9_out(
    const float* __restrict__ hf,
    const float* __restrict__ pfs, const float* __restrict__ pfq,
    const float* __restrict__ gammaf, const float* __restrict__ betaf,
    float* __restrict__ out)
{
    const int blk = blockIdx.x, t = threadIdx.x;
    float S = 0.f, Q = 0.f;
    #pragma unroll 8
    for (int i = 0; i < 64; ++i) {
        S += pfs[(size_t)i*384 + t];
        Q += pfq[(size_t)i*384 + t];
    }
    const float mu  = S * (1.f/1024.f);
    const float var = Q * (1.f/1024.f) - mu*mu;
    const float sc  = gammaf[t] * rsqrtf(var + EPS);
    const float sh  = betaf[t] - mu * sc;
    const size_t base = (size_t)blk * 8 * 384;
    #pragma unroll
    for (int g = 0; g < 8; ++g) {
        float v = fmaf(hf[base + g*384 + t], sc, sh);
        out[base + g*384 + t] = fmaxf(v, 0.f);
    }
}

extern "C" void kernel_launch(void* const* d_in, const int* in_sizes, int n_in,
                              void* d_out, int out_size, void* d_ws, size_t ws_size,
                              hipStream_t stream) {
    const float* pg      = (const float*)d_in[0];
    const float* W1      = (const float*)d_in[1];
    const float* b1      = (const float*)d_in[2];
    const float* gamma1  = (const float*)d_in[3];
    const float* beta1   = (const float*)d_in[4];
    const float* W2      = (const float*)d_in[5];
    const float* b2      = (const float*)d_in[6];
    const float* W3      = (const float*)d_in[7];
    const float* b3      = (const float*)d_in[8];
    const float* gamma3  = (const float*)d_in[9];
    const float* beta3   = (const float*)d_in[10];
    const float* W4      = (const float*)d_in[11];
    const float* b4      = (const float*)d_in[12];
    const float* alpha   = (const float*)d_in[13];
    const float* beta_af = (const float*)d_in[14];
    const float* Wf      = (const float*)d_in[15];
    const float* bf      = (const float*)d_in[16];
    const float* gammaf  = (const float*)d_in[17];
    const float* betaf   = (const float*)d_in[18];
    float* out = (float*)d_out;

    float* w = (float*)d_ws;
    unsigned short* h3b = (unsigned short*)w; w += 1024*16384/2;      // 32 MB bf16 (k35-internal, L2-hot readback)
    unsigned short* W2b = (unsigned short*)w; w += 32768/2;
    unsigned short* W3b = (unsigned short*)w; w += 262144/2;
    unsigned short* W4b = (unsigned short*)w; w += 196608/2;
    unsigned short* Wfb = (unsigned short*)w; w += 294912/2;
    float* hf     = w;  w += 1024*384;
    float* fg2    = w;  w += 1024*384;
    float* A      = w;  w += 1024*384;
    float* mom    = w;  w += 12*1024;    // [9][1024] point-moment partials
    float* p3sb   = w;  w += 16*512;     // atomic bins (zeroed by k1_prep)
    float* p3qb   = w;  w += 16*512;
    float* pfs    = w;  w += 64*384;     // [slice][o]
    float* pfq    = w;  w += 64*384;
    float* S1p    = w;  w += 1024;
    float* S2p    = w;  w += 1024;
    int*   idxw   = (int*)w;  w += 1024*256;
    unsigned* barcnt = (unsigned*)w; w += 2;

    hipLaunchKernelGGL(k1_prep, dim3(1024 + 2304), dim3(128), 0, stream,
                       pg, W2, W3, W4, Wf,
                       mom, idxw, W2b, W3b, W4b, Wfb, p3sb, p3qb, barcnt);
    hipLaunchKernelGGL(k35_fused, dim3(512), dim3(1024), 0, stream,
                       pg, W1, b1, gamma1, beta1, mom, W2b, b2, W3b, b3,
                       gamma3, beta3, W4b, b4, idxw,
                       h3b, p3sb, p3qb, barcnt, fg2, A, S1p, S2p);
    hipLaunchKernelGGL(k7_fused, dim3(256), dim3(384), 0, stream,
                       fg2, A, alpha, beta_af, S1p, S2p, Wfb, bf, hf, pfs, pfq);
    hipLaunchKernelGGL(k9_out, dim3(128), dim3(384), 0, stream,
                       hf, pfs, pfq, gammaf, betaf, out);
}

// Round 16
// 194.152 us; speedup vs baseline: 1.6366x; 1.6366x over previous
//
#include <hip/hip_runtime.h>
#include <math.h>

#define EPS 1e-5f

typedef __attribute__((ext_vector_type(8))) short s16x8;   // 8 bf16 (4 VGPRs)
typedef __attribute__((ext_vector_type(4))) float f32x4;   // MFMA C/D

__device__ __forceinline__ unsigned short f2bf(float x) {
    unsigned u = __float_as_uint(x);
    u += 0x7fffu + ((u >> 16) & 1u);           // round-to-nearest-even
    return (unsigned short)(u >> 16);
}
__device__ __forceinline__ float bf2f(unsigned short h) {
    return __uint_as_float(((unsigned)h) << 16);
}
__device__ __forceinline__ unsigned long long pack4bf(float a, float b, float c, float d) {
    return (unsigned long long)f2bf(a)
         | ((unsigned long long)f2bf(b) << 16)
         | ((unsigned long long)f2bf(c) << 32)
         | ((unsigned long long)f2bf(d) << 48);
}

// ---- DPP width-16 reductions (pure VALU, no LDS pipe)
template<int CTRL>
__device__ __forceinline__ float dppmov(float x) {
    return __int_as_float(__builtin_amdgcn_update_dpp(
        0, __float_as_int(x), CTRL, 0xF, 0xF, true));
}
__device__ __forceinline__ float red16_sum(float x) {
    x += dppmov<0xB1>(x);
    x += dppmov<0x4E>(x);
    x += dppmov<0x141>(x);
    x += dppmov<0x140>(x);
    return x;
}
__device__ __forceinline__ float red16_max(float x) {
    x = fmaxf(x, dppmov<0xB1>(x));
    x = fmaxf(x, dppmov<0x4E>(x));
    x = fmaxf(x, dppmov<0x141>(x));
    x = fmaxf(x, dppmov<0x140>(x));
    return x;
}

// ---------------------------------------------------------------- K1: knn + point moments + weight bf16 conversion + bin zeroing.
__global__ __launch_bounds__(128) void k1_prep(
    const float* __restrict__ pg,
    const float* __restrict__ W2, const float* __restrict__ W3,
    const float* __restrict__ W4, const float* __restrict__ Wf,
    float* __restrict__ mom, int* __restrict__ idxw,
    unsigned short* __restrict__ W2b, unsigned short* __restrict__ W3b,
    unsigned short* __restrict__ W4b, unsigned short* __restrict__ Wfb,
    float* __restrict__ p3sb, float* __restrict__ p3qb)
{
    __shared__ float pgs[96];
    __shared__ float sqs[32];
    if (blockIdx.x >= 1024) {
        const int wb = blockIdx.x - 1024;
        const int i = wb * 128 + threadIdx.x;
        if (i < 32768)  W2b[i] = f2bf(W2[i]);
        if (i < 262144) W3b[i] = f2bf(W3[i]);
        if (i < 196608) W4b[i] = f2bf(W4[i]);
        if (i < 294912) Wfb[i] = f2bf(Wf[i]);
        if (wb < 16) {
            for (int j = threadIdx.x; j < 512; j += 128) {
                p3sb[wb*512 + j] = 0.f;
                p3qb[wb*512 + j] = 0.f;
            }
        }
        return;
    }
    const int b = blockIdx.x;
    const int t = threadIdx.x;
    if (t < 96) pgs[t] = pg[b * 96 + t];
    __syncthreads();
    if (t < 32) {
        float x = pgs[t*3+0], y = pgs[t*3+1], z = pgs[t*3+2];
        sqs[t] = x*x + y*y + z*z;
    }
    __syncthreads();
    if (t < 32) {
        const float x = pgs[t*3+0], y = pgs[t*3+1], z = pgs[t*3+2];
        float v[9] = {x, y, z, x*x, x*y, x*z, y*y, y*z, z*z};
        #pragma unroll
        for (int off = 16; off > 0; off >>= 1)
            #pragma unroll
            for (int j = 0; j < 9; ++j)
                v[j] += __shfl_down(v[j], off, 32);
        if (t == 0) {
            #pragma unroll
            for (int j = 0; j < 9; ++j)
                mom[j*1024 + b] = v[j];
        }
        const float sql = sqs[t];
        float dist[32];
        #pragma unroll
        for (int m = 0; m < 32; ++m) {
            float dot = x*pgs[m*3+0] + y*pgs[m*3+1] + z*pgs[m*3+2];
            dist[m] = sql + sqs[m] - 2.f*dot;
        }
        unsigned used = 0u;
        int* orow = idxw + b*256 + t*8;
        #pragma unroll
        for (int j = 0; j < 8; ++j) {
            float best = 3.4e38f; int bi = 0;
            #pragma unroll
            for (int m = 0; m < 32; ++m) {
                if (!((used >> m) & 1u) && dist[m] < best) { best = dist[m]; bi = m; }
            }
            used |= (1u << bi);
            orow[j] = bi;
        }
    }
}

// ---------------------------------------------------------------- K3: 1024 threads, 16 waves. (R13 passing version)
__global__ __launch_bounds__(1024, 8) void k3_mfma(
    const float* __restrict__ pg,
    const float* __restrict__ W1, const float* __restrict__ b1,
    const float* __restrict__ gamma1, const float* __restrict__ beta1,
    const float* __restrict__ mom,
    const unsigned short* __restrict__ W2b, const float* __restrict__ b2,
    const unsigned short* __restrict__ W3b, const float* __restrict__ b3,
    unsigned short* __restrict__ h3b,
    float* __restrict__ p3sb, float* __restrict__ p3qb)
{
    const int g0 = blockIdx.x * 2;
    const int t = threadIdx.x;
    __shared__ __align__(16) unsigned short SB[26128];   // 52256 B
    unsigned short* B1  = SB;            // [64][136] conv2 staging (persistent)
    unsigned short* F2  = SB + 8704;     // [64][264] f2, conv3 B-matrix (disjoint)
    unsigned short* FGB = SB + 25600;    // [2][264] fg per group (bf16)
    __shared__ __align__(16) float sc1s[128], sh1s[128];
    __shared__ __align__(16) float W1s[384], b1s[128];
    __shared__ __align__(16) float pgs3[192];
    __shared__ float momS[9];

    if (t < 192) pgs3[t] = pg[g0*96 + t];
    if (t < 384) W1s[t] = W1[t];
    if (t < 128) b1s[t] = b1[t];
    {
        const int wv = t >> 6, ln = t & 63;
        if (wv < 9) {
            float s = 0.f;
            #pragma unroll
            for (int i = 0; i < 16; ++i)
                s += mom[wv*1024 + ln + 64*i];
            #pragma unroll
            for (int off = 32; off > 0; off >>= 1)
                s += __shfl_down(s, off, 64);
            if (ln == 0) momS[wv] = s;
        }
    }
    __syncthreads();

    if (t < 128) {
        const float Sx = momS[0], Sy = momS[1], Sz = momS[2];
        const float Sxx = momS[3], Sxy = momS[4], Sxz = momS[5];
        const float Syy = momS[6], Syz = momS[7], Szz = momS[8];
        const float w0 = W1s[t*3+0], w1 = W1s[t*3+1], w2 = W1s[t*3+2];
        const float bb = b1s[t];
        const float N = 32768.f;
        const float wd = w0*Sx + w1*Sy + w2*Sz;
        const float S = wd + N*bb;
        const float Q = w0*w0*Sxx + w1*w1*Syy + w2*w2*Szz
                      + 2.f*(w0*w1*Sxy + w0*w2*Sxz + w1*w2*Syz)
                      + 2.f*bb*wd + N*bb*bb;
        const float mu  = S * (1.f/32768.f);
        const float var = Q * (1.f/32768.f) - mu*mu;
        const float sc  = gamma1[t] * rsqrtf(var + EPS);
        sc1s[t] = sc;
        sh1s[t] = beta1[t] - mu * sc;
    }
    __syncthreads();

    {
        const int l = t >> 4, c0 = (t & 15) * 8;
        const float px = pgs3[l*3+0], py = pgs3[l*3+1], pz = pgs3[l*3+2];
        unsigned short ov[8];
        #pragma unroll
        for (int e = 0; e < 8; ++e) {
            const int c = c0 + e;
            float v = fmaf(W1s[c*3+2], pz, fmaf(W1s[c*3+1], py, fmaf(W1s[c*3+0], px, b1s[c])));
            float val = fmaxf(fmaf(v, sc1s[c], sh1s[c]), 0.f);
            ov[e] = f2bf(val);
        }
        uint4 o4;
        o4.x = (unsigned)ov[0] | ((unsigned)ov[1] << 16);
        o4.y = (unsigned)ov[2] | ((unsigned)ov[3] << 16);
        o4.z = (unsigned)ov[4] | ((unsigned)ov[5] << 16);
        o4.w = (unsigned)ov[6] | ((unsigned)ov[7] << 16);
        *(uint4*)&B1[l*136 + c0] = o4;
    }
    __syncthreads();

    const int wave = t >> 6;      // 0..15
    const int lane = t & 63;
    const int m    = lane & 15;
    const int quad = lane >> 4;

    f32x4 acc2[4];
    #pragma unroll
    for (int n = 0; n < 4; ++n)
        acc2[n] = (f32x4){0.f, 0.f, 0.f, 0.f};

    #pragma unroll
    for (int kt = 0; kt < 4; ++kt) {
        s16x8 bv[4];
        #pragma unroll
        for (int nt = 0; nt < 4; ++nt)
            bv[nt] = *(const s16x8*)&B1[(nt*16 + m)*136 + kt*32 + quad*8];
        s16x8 av = *(const s16x8*)(W2b + (size_t)(wave*16 + m)*128 + kt*32 + quad*8);
        #pragma unroll
        for (int nt = 0; nt < 4; ++nt)
            acc2[nt] = __builtin_amdgcn_mfma_f32_16x16x32_bf16(av, bv[nt], acc2[nt], 0, 0, 0);
    }

    {
        const int o0 = wave*16 + quad*4;
        #pragma unroll
        for (int r = 0; r < 4; ++r) {
            float bb = b2[o0 + r];
            #pragma unroll
            for (int nt = 0; nt < 4; ++nt) acc2[nt][r] += bb;
        }
        #pragma unroll
        for (int nt = 0; nt < 4; ++nt) {
            const int row = nt*16 + m;
            *(unsigned long long*)&F2[row*264 + o0] =
                pack4bf(acc2[nt][0], acc2[nt][1], acc2[nt][2], acc2[nt][3]);
        }
        float f0[4], f1[4];
        #pragma unroll
        for (int r = 0; r < 4; ++r) {
            f0[r] = red16_max(fmaxf(acc2[0][r], acc2[1][r]));
            f1[r] = red16_max(fmaxf(acc2[2][r], acc2[3][r]));
        }
        if (m == 0) {
            *(unsigned long long*)&FGB[o0]       = pack4bf(f0[0], f0[1], f0[2], f0[3]);
            *(unsigned long long*)&FGB[264 + o0] = pack4bf(f1[0], f1[1], f1[2], f1[3]);
        }
    }
    __syncthreads();   // F2 + FGB complete

    unsigned short* dst = h3b + (size_t)blockIdx.x * 32768;
    const int binbase = (blockIdx.x & 15) * 512;
    #pragma unroll
    for (int mt = 0; mt < 2; ++mt) {
        const int ot = wave*2 + mt;          // 0..31
        const int o0 = ot*16 + quad*4;

        f32x4 facc = (f32x4){0.f, 0.f, 0.f, 0.f};
        #pragma unroll
        for (int kt = 0; kt < 8; ++kt) {
            s16x8 bg = *(const s16x8*)&FGB[(m & 1)*264 + kt*32 + quad*8];
            s16x8 av = *(const s16x8*)(W3b + (size_t)(ot*16 + m)*512 + kt*32 + quad*8);
            facc = __builtin_amdgcn_mfma_f32_16x16x32_bf16(av, bg, facc, 0, 0, 0);
        }

        f32x4 acc3[4];
        #pragma unroll
        for (int r = 0; r < 4; ++r) {
            float self = facc[r];
            float oth  = dppmov<0xB1>(self);        // value from lane m^1
            float fg_g0 = (m & 1) ? oth : self;
            float fg_g1 = (m & 1) ? self : oth;
            float bb = b3[o0 + r];
            acc3[0][r] = bb + fg_g0;
            acc3[1][r] = bb + fg_g0;
            acc3[2][r] = bb + fg_g1;
            acc3[3][r] = bb + fg_g1;
        }

        #pragma unroll
        for (int kt = 0; kt < 8; ++kt) {
            s16x8 bv[4];
            #pragma unroll
            for (int nt = 0; nt < 4; ++nt)
                bv[nt] = *(const s16x8*)&F2[(nt*16 + m)*264 + kt*32 + quad*8];
            s16x8 av = *(const s16x8*)(W3b + (size_t)(ot*16 + m)*512 + 256 + kt*32 + quad*8);
            #pragma unroll
            for (int nt = 0; nt < 4; ++nt)
                acc3[nt] = __builtin_amdgcn_mfma_f32_16x16x32_bf16(av, bv[nt], acc3[nt], 0, 0, 0);
        }

        float s[4], q[4];
        #pragma unroll
        for (int r = 0; r < 4; ++r) {
            float x0 = acc3[0][r], x1 = acc3[1][r];
            float x2 = acc3[2][r], x3 = acc3[3][r];
            s[r] = (x0 + x1) + (x2 + x3);
            q[r] = (x0*x0 + x1*x1) + (x2*x2 + x3*x3);
        }
        {
            unsigned long long u0 = pack4bf(acc3[0][0], acc3[0][1], acc3[0][2], acc3[0][3]);
            unsigned long long u1 = pack4bf(acc3[1][0], acc3[1][1], acc3[1][2], acc3[1][3]);
            unsigned long long u2 = pack4bf(acc3[2][0], acc3[2][1], acc3[2][2], acc3[2][3]);
            unsigned long long u3 = pack4bf(acc3[3][0], acc3[3][1], acc3[3][2], acc3[3][3]);
            unsigned short* p = dst + (size_t)(ot*64 + lane) * 16;
            *(uint4*)(p)     = make_uint4((unsigned)u0, (unsigned)(u0 >> 32), (unsigned)u1, (unsigned)(u1 >> 32));
            *(uint4*)(p + 8) = make_uint4((unsigned)u2, (unsigned)(u2 >> 32), (unsigned)u3, (unsigned)(u3 >> 32));
        }
        #pragma unroll
        for (int r = 0; r < 4; ++r) {
            s[r] = red16_sum(s[r]);
            q[r] = red16_sum(q[r]);
        }
        if (m == 0) {
            #pragma unroll
            for (int r = 0; r < 4; ++r) {
                atomicAdd(&p3sb[binbase + o0 + r], s[r]);
                atomicAdd(&p3qb[binbase + o0 + r], q[r]);
            }
        }
    }
}

// ---------------------------------------------------------------- K5: 12 waves (768 thr), 2 mt/wave -> 24 waves/CU. (R14 passing version)
__global__ __launch_bounds__(768, 6) void k5_mfma(
    const unsigned short* __restrict__ h3b,
    const float* __restrict__ gamma3, const float* __restrict__ beta3,
    const float* __restrict__ p3sb, const float* __restrict__ p3qb,
    const unsigned short* __restrict__ W4b, const float* __restrict__ b4,
    const int* __restrict__ idxw,
    float* __restrict__ fg2, float* __restrict__ A,
    float* __restrict__ S1p, float* __restrict__ S2p)
{
    const int g0 = blockIdx.x * 2;
    const int t = threadIdx.x;
    __shared__ __align__(16) unsigned short SB[33280];   // 66560 B
    unsigned short* B4 = SB;                              // [64][520] staging
    unsigned short* XT = SB;                              // [g][o*40 + l], g stride 15360
    unsigned short* Mm = SB + 30720;                      // [g][l*40 + m], g stride 1280
    __shared__ __align__(16) float sc3s[512], sh3s[512];
    __shared__ int icnt[2][32];
    __shared__ float r1[2][12], r2[2][12];

    if (t < 512) {
        float S = 0.f, Q = 0.f;
        #pragma unroll
        for (int bb = 0; bb < 16; ++bb) {
            S += p3sb[bb*512 + t];
            Q += p3qb[bb*512 + t];
        }
        float mu  = S * (1.f/32768.f);
        float var = Q * (1.f/32768.f) - mu*mu;
        float sc  = gamma3[t] * rsqrtf(var + EPS);
        sc3s[t] = sc;
        sh3s[t] = beta3[t] - mu * sc;
    }
    if (t < 64) icnt[t >> 5][t & 31] = 0;
    __syncthreads();

    {
        const uint4* src = (const uint4*)(h3b + (size_t)blockIdx.x * 32768);
        for (int i = t; i < 4096; i += 768) {
            uint4 hv = src[i];
            const int flat16 = i >> 1, half = i & 1;
            const int ln = flat16 & 63, m2 = ln & 15, q2 = ln >> 4;
            const int wm = flat16 >> 6;
            const int o0 = wm*16 + q2*4;
            const float4 sc = *(const float4*)&sc3s[o0];
            const float4 sh = *(const float4*)&sh3s[o0];
            const int rowa = (half*2)*16 + m2;
            float a0 = fmaxf(fmaf(bf2f((unsigned short)(hv.x       )), sc.x, sh.x), 0.f);
            float a1 = fmaxf(fmaf(bf2f((unsigned short)(hv.x >> 16 )), sc.y, sh.y), 0.f);
            float a2 = fmaxf(fmaf(bf2f((unsigned short)(hv.y       )), sc.z, sh.z), 0.f);
            float a3 = fmaxf(fmaf(bf2f((unsigned short)(hv.y >> 16 )), sc.w, sh.w), 0.f);
            float b0 = fmaxf(fmaf(bf2f((unsigned short)(hv.z       )), sc.x, sh.x), 0.f);
            float b1 = fmaxf(fmaf(bf2f((unsigned short)(hv.z >> 16 )), sc.y, sh.y), 0.f);
            float b2 = fmaxf(fmaf(bf2f((unsigned short)(hv.w       )), sc.z, sh.z), 0.f);
            float b3 = fmaxf(fmaf(bf2f((unsigned short)(hv.w >> 16 )), sc.w, sh.w), 0.f);
            *(unsigned long long*)&B4[rowa*520 + o0]        = pack4bf(a0, a1, a2, a3);
            *(unsigned long long*)&B4[(rowa + 16)*520 + o0] = pack4bf(b0, b1, b2, b3);
        }
    }
    __syncthreads();

    const int wave = t >> 6;      // 0..11
    const int lane = t & 63;
    const int m    = lane & 15;
    const int quad = lane >> 4;

    f32x4 acc4[2][4];
    #pragma unroll
    for (int mt = 0; mt < 2; ++mt)
        #pragma unroll
        for (int n = 0; n < 4; ++n)
            acc4[mt][n] = (f32x4){0.f, 0.f, 0.f, 0.f};

    #pragma unroll 4
    for (int kt = 0; kt < 16; ++kt) {
        s16x8 bv[4];
        #pragma unroll
        for (int nt = 0; nt < 4; ++nt)
            bv[nt] = *(const s16x8*)&B4[(nt*16 + m)*520 + kt*32 + quad*8];
        #pragma unroll
        for (int mt = 0; mt < 2; ++mt) {
            s16x8 av = *(const s16x8*)(W4b + (size_t)(wave*32 + mt*16 + m)*512 + kt*32 + quad*8);
            #pragma unroll
            for (int nt = 0; nt < 4; ++nt)
                acc4[mt][nt] = __builtin_amdgcn_mfma_f32_16x16x32_bf16(av, bv[nt], acc4[mt][nt], 0, 0, 0);
        }
    }

    #pragma unroll
    for (int mt = 0; mt < 2; ++mt) {
        const int o0 = wave*32 + mt*16 + quad*4;
        float f0[4], f1[4];
        #pragma unroll
        for (int r = 0; r < 4; ++r) {
            float bb = b4[o0 + r];
            #pragma unroll
            for (int nt = 0; nt < 4; ++nt) acc4[mt][nt][r] += bb;
            f0[r] = red16_max(fmaxf(acc4[mt][0][r], acc4[mt][1][r]));
            f1[r] = red16_max(fmaxf(acc4[mt][2][r], acc4[mt][3][r]));
        }
        if (m == 0) {
            #pragma unroll
            for (int r = 0; r < 4; ++r) {
                fg2[(size_t)g0*384 + o0 + r]     = f0[r];
                fg2[(size_t)(g0+1)*384 + o0 + r] = f1[r];
            }
        }
    }
    __syncthreads();

    #pragma unroll
    for (int mt = 0; mt < 2; ++mt) {
        const int o0 = wave*32 + mt*16 + quad*4;
        #pragma unroll
        for (int nt = 0; nt < 4; ++nt) {
            const int g = nt >> 1;
            const int l = (nt & 1)*16 + m;
            unsigned short* xg = XT + g*15360;
            #pragma unroll
            for (int r = 0; r < 4; ++r)
                xg[(o0 + r)*40 + l] = f2bf(acc4[mt][nt][r]);
        }
    }
    if (t < 64) {
        const int g = t >> 5, l = t & 31;
        uint4 z = make_uint4(0u, 0u, 0u, 0u);
        #pragma unroll
        for (int i = 0; i < 5; ++i)
            *(uint4*)&Mm[g*1280 + l*40 + i*8] = z;
    }
    __syncthreads();

    if (t < 64) {
        const int g = t >> 5, l = t & 31;
        const int* ip = idxw + (size_t)(g0 + g)*256 + l*8;
        #pragma unroll
        for (int j = 0; j < 8; ++j) {
            int ix = ip[j];
            Mm[g*1280 + l*40 + ix] = 0x3F80;
            atomicAdd(&icnt[g][ix], 1);
        }
    }
    __syncthreads();

    float s1loc[2] = {0.f, 0.f}, s2loc[2] = {0.f, 0.f};
    #pragma unroll
    for (int g = 0; g < 2; ++g) {
        const float c0 = (float)icnt[g][m];
        const float c1 = (float)icnt[g][m + 16];
        const float w0 = c0 - 8.f, u0 = c0 + 8.f;
        const float w1 = c1 - 8.f, u1 = c1 + 8.f;
        #pragma unroll
        for (int mt = 0; mt < 2; ++mt) {
            const int o0 = wave*32 + mt*16 + quad*4;
            float Ap[4];
            #pragma unroll
            for (int r = 0; r < 4; ++r) {
                const float x0 = acc4[mt][g*2 + 0][r];
                const float x1 = acc4[mt][g*2 + 1][r];
                Ap[r] = w0*x0 + w1*x1;
                s1loc[g] += Ap[r];
                s2loc[g] += u0*x0*x0 + u1*x1*x1;
            }
            #pragma unroll
            for (int r = 0; r < 4; ++r)
                Ap[r] = red16_sum(Ap[r]);
            if (m == 0) {
                #pragma unroll
                for (int r = 0; r < 4; ++r)
                    A[(size_t)(g0 + g)*384 + o0 + r] = Ap[r];
            }
        }
    }

    #pragma unroll
    for (int g = 0; g < 2; ++g) {
        const unsigned short* xg = XT + g*15360;
        float cross = 0.f;
        #pragma unroll
        for (int lt = 0; lt < 2; ++lt) {
            s16x8 af = *(const s16x8*)&Mm[g*1280 + (lt*16 + m)*40 + quad*8];
            #pragma unroll
            for (int i = 0; i < 2; ++i) {
                const int oc = (wave*2 + i)*16 + m;
                s16x8 bfv = *(const s16x8*)&xg[oc*40 + quad*8];
                f32x4 sa = __builtin_amdgcn_mfma_f32_16x16x32_bf16(
                    af, bfv, (f32x4){0.f, 0.f, 0.f, 0.f}, 0, 0, 0);
                #pragma unroll
                for (int r = 0; r < 4; ++r) {
                    const int lp = lt*16 + quad*4 + r;
                    cross = fmaf(bf2f(xg[oc*40 + lp]), sa[r], cross);
                }
            }
        }
        s2loc[g] -= 2.f * cross;
    }

    #pragma unroll
    for (int g = 0; g < 2; ++g) {
        float sA = s1loc[g], sQ = s2loc[g];
        #pragma unroll
        for (int off = 32; off > 0; off >>= 1) {
            sA += __shfl_down(sA, off, 64);
            sQ += __shfl_down(sQ, off, 64);
        }
        if (lane == 0) { r1[g][wave] = sA; r2[g][wave] = sQ; }
    }
    __syncthreads();
    if (t < 2) {
        float S = 0.f, Q = 0.f;
        #pragma unroll
        for (int w = 0; w < 12; ++w) { S += r1[t][w]; Q += r2[t][w]; }
        S1p[g0 + t] = S;
        S2p[g0 + t] = Q;
    }
}

// ---------------------------------------------------------------- K7: head GEMM, M split 4-ways -> grid 256.
__global__ __launch_bounds__(384) void k7_fused(
    const float* __restrict__ fg2, const float* __restrict__ A,
    const float* __restrict__ alpha, const float* __restrict__ beta_aff,
    const float* __restrict__ S1p, const float* __restrict__ S2p,
    const unsigned short* __restrict__ Wfb, const float* __restrict__ bf,
    float* __restrict__ hf, float* __restrict__ pfs, float* __restrict__ pfq)
{
    const int blk    = blockIdx.x;
    const int slice  = blk >> 2;          // 0..63 (group slice)
    const int msplit = blk & 3;           // 0..3  (channel quarter)
    const int g0     = slice * 16;
    const int obase  = msplit * 96;
    const int t = threadIdx.x;
    __shared__ __align__(16) char smem[24832];
    unsigned short* xfb = (unsigned short*)smem;   // [16][776] bf16 inputs
    float* OTf = (float*)smem;                     // [16][100] fp32 out (aliases xfb, sync'd)
    __shared__ double rs[6], rq[6];
    __shared__ float stdsh;

    {
        double s = 0.0, q = 0.0;
        for (int i = t; i < 1024; i += 384) { s += (double)S1p[i]; q += (double)S2p[i]; }
        #pragma unroll
        for (int off = 32; off > 0; off >>= 1) {
            s += __shfl_down(s, off, 64);
            q += __shfl_down(q, off, 64);
        }
        if ((t & 63) == 0) { rs[t >> 6] = s; rq[t >> 6] = q; }
        __syncthreads();
        if (t == 0) {
            double S = 0.0, Q = 0.0;
            #pragma unroll
            for (int w = 0; w < 6; ++w) { S += rs[w]; Q += rq[w]; }
            const double N = 1024.0 * 32.0 * 8.0 * 384.0;
            double var = (Q - S*S/N) / (N - 1.0);
            stdsh = (float)sqrt(var);
        }
        __syncthreads();
    }
    const float inv = 1.f / (256.f * (stdsh + EPS));

    for (int i = t; i < 16*96; i += 384) {
        const int row = i / 96, c8 = (i % 96) * 8;
        const int g = g0 + row;
        float e[8];
        if (c8 < 384) {
            const float4* s0 = (const float4*)(fg2 + (size_t)g*384 + c8);
            float4 v0 = s0[0], v1 = s0[1];
            e[0]=v0.x; e[1]=v0.y; e[2]=v0.z; e[3]=v0.w;
            e[4]=v1.x; e[5]=v1.y; e[6]=v1.z; e[7]=v1.w;
        } else {
            const int cc = c8 - 384;
            const float4* s0 = (const float4*)(A + (size_t)g*384 + cc);
            float4 v0 = s0[0], v1 = s0[1];
            float av[8] = {v0.x,v0.y,v0.z,v0.w,v1.x,v1.y,v1.z,v1.w};
            #pragma unroll
            for (int j = 0; j < 8; ++j)
                e[j] = fmaf(alpha[cc+j] * inv, av[j], beta_aff[cc+j]);
        }
        uint4 o4;
        o4.x = (unsigned)f2bf(e[0]) | ((unsigned)f2bf(e[1]) << 16);
        o4.y = (unsigned)f2bf(e[2]) | ((unsigned)f2bf(e[3]) << 16);
        o4.z = (unsigned)f2bf(e[4]) | ((unsigned)f2bf(e[5]) << 16);
        o4.w = (unsigned)f2bf(e[6]) | ((unsigned)f2bf(e[7]) << 16);
        *(uint4*)&xfb[row*776 + c8] = o4;
    }
    __syncthreads();

    const int wave = t >> 6;      // 0..5
    const int lane = t & 63;
    const int m    = lane & 15;
    const int quad = lane >> 4;

    f32x4 acc = (f32x4){0.f, 0.f, 0.f, 0.f};
    #pragma unroll 4
    for (int kt = 0; kt < 24; ++kt) {
        s16x8 bv = *(const s16x8*)&xfb[m*776 + kt*32 + quad*8];
        s16x8 av = *(const s16x8*)(Wfb + (size_t)(obase + wave*16 + m)*768 + kt*32 + quad*8);
        acc = __builtin_amdgcn_mfma_f32_16x16x32_bf16(av, bv, acc, 0, 0, 0);
    }

    {
        const int o0 = obase + wave*16 + quad*4;
        float s[4], q[4];
        #pragma unroll
        for (int r = 0; r < 4; ++r) {
            acc[r] += bf[o0 + r];
            s[r] = red16_sum(acc[r]);
            q[r] = red16_sum(acc[r]*acc[r]);
        }
        if (m == 0) {
            #pragma unroll
            for (int r = 0; r < 4; ++r) {
                pfs[(size_t)slice*384 + o0 + r] = s[r];
                pfq[(size_t)slice*384 + o0 + r] = q[r];
            }
        }
    }
    __syncthreads();   // xfb reads done; smem becomes OTf

    {
        const int lo0 = wave*16 + quad*4;     // local channel 0..95
        #pragma unroll
        for (int r = 0; r < 4; ++r)
            OTf[m*100 + lo0 + r] = acc[r];
    }
    __syncthreads();

    {
        const int grp = t / 24, c4 = t % 24;
        float4 v = *(const float4*)&OTf[grp*100 + c4*4];
        *(float4*)(hf + (size_t)(g0 + grp)*384 + obase + c4*4) = v;
    }
}

// ---------------------------------------------------------------- K9: fused BNf finalize (redundant per-block) + relu -> out
__global__ __launch_bounds__(384) void k9_out(
    const float* __restrict__ hf,
    const float* __restrict__ pfs, const float* __restrict__ pfq,
    const float* __restrict__ gammaf, const float* __restrict__ betaf,
    float* __restrict__ out)
{
    const int blk = blockIdx.x, t = threadIdx.x;
    float S = 0.f, Q = 0.f;
    #pragma unroll 8
    for (int i = 0; i < 64; ++i) {
        S += pfs[(size_t)i*384 + t];
        Q += pfq[(size_t)i*384 + t];
    }
    const float mu  = S * (1.f/1024.f);
    const float var = Q * (1.f/1024.f) - mu*mu;
    const float sc  = gammaf[t] * rsqrtf(var + EPS);
    const float sh  = betaf[t] - mu * sc;
    const size_t base = (size_t)blk * 8 * 384;
    #pragma unroll
    for (int g = 0; g < 8; ++g) {
        float v = fmaf(hf[base + g*384 + t], sc, sh);
        out[base + g*384 + t] = fmaxf(v, 0.f);
    }
}

extern "C" void kernel_launch(void* const* d_in, const int* in_sizes, int n_in,
                              void* d_out, int out_size, void* d_ws, size_t ws_size,
                              hipStream_t stream) {
    const float* pg      = (const float*)d_in[0];
    const float* W1      = (const float*)d_in[1];
    const float* b1      = (const float*)d_in[2];
    const float* gamma1  = (const float*)d_in[3];
    const float* beta1   = (const float*)d_in[4];
    const float* W2      = (const float*)d_in[5];
    const float* b2      = (const float*)d_in[6];
    const float* W3      = (const float*)d_in[7];
    const float* b3      = (const float*)d_in[8];
    const float* gamma3  = (const float*)d_in[9];
    const float* beta3   = (const float*)d_in[10];
    const float* W4      = (const float*)d_in[11];
    const float* b4      = (const float*)d_in[12];
    const float* alpha   = (const float*)d_in[13];
    const float* beta_af = (const float*)d_in[14];
    const float* Wf      = (const float*)d_in[15];
    const float* bf      = (const float*)d_in[16];
    const float* gammaf  = (const float*)d_in[17];
    const float* betaf   = (const float*)d_in[18];
    float* out = (float*)d_out;

    float* w = (float*)d_ws;
    unsigned short* h3b = (unsigned short*)w; w += 1024*16384/2;      // 32 MB bf16, fragment order
    unsigned short* W2b = (unsigned short*)w; w += 32768/2;
    unsigned short* W3b = (unsigned short*)w; w += 262144/2;
    unsigned short* W4b = (unsigned short*)w; w += 196608/2;
    unsigned short* Wfb = (unsigned short*)w; w += 294912/2;
    float* hf     = w;  w += 1024*384;
    float* fg2    = w;  w += 1024*384;
    float* A      = w;  w += 1024*384;
    float* mom    = w;  w += 12*1024;    // [9][1024] point-moment partials (plain stores)
    float* p3sb   = w;  w += 16*512;     // atomic bins, XCD-local (zeroed by k1_prep)
    float* p3qb   = w;  w += 16*512;
    float* pfs    = w;  w += 64*384;     // [slice][o]
    float* pfq    = w;  w += 64*384;
    float* S1p    = w;  w += 1024;
    float* S2p    = w;  w += 1024;
    int*   idxw   = (int*)w;  w += 1024*256;

    hipLaunchKernelGGL(k1_prep, dim3(1024 + 2304), dim3(128), 0, stream,
                       pg, W2, W3, W4, Wf,
                       mom, idxw, W2b, W3b, W4b, Wfb, p3sb, p3qb);
    hipLaunchKernelGGL(k3_mfma, dim3(512), dim3(1024), 0, stream,
                       pg, W1, b1, gamma1, beta1, mom, W2b, b2, W3b, b3,
                       h3b, p3sb, p3qb);
    hipLaunchKernelGGL(k5_mfma, dim3(512), dim3(768), 0, stream,
                       h3b, gamma3, beta3, p3sb, p3qb, W4b, b4, idxw,
                       fg2, A, S1p, S2p);
    hipLaunchKernelGGL(k7_fused, dim3(256), dim3(384), 0, stream,
                       fg2, A, alpha, beta_af, S1p, S2p, Wfb, bf, hf, pfs, pfq);
    hipLaunchKernelGGL(k9_out, dim3(128), dim3(384), 0, stream,
                       hf, pfs, pfq, gammaf, betaf, out);
}